// Round 8
// baseline (517.677 us; speedup 1.0000x reference)
//
#include <hip/hip_runtime.h>
#include <hip/hip_bf16.h>

// ---------------------------------------------------------------------------
// 2-layer GAT on MI355X (gfx950).
// R7: XCD-local gathers. agg kernels split the channel dim into 8 slices
//     (slice = blockIdx & 7 -> XCD); each slice's h-column block (3.2 MB)
//     fits one XCD's 4 MiB L2, killing the 8x cross-XCD refetch that made
//     R7's FETCH_SIZE 195 MB vs the ~43 MB ideal. alpha1 now [head][edge].
// ---------------------------------------------------------------------------

#define IN_DIM   256
#define HID      256
#define HEADS    4
#define C1       64
#define OUT_DIM  128
#define NEG_SLOPE 0.2f

using short8 = __attribute__((ext_vector_type(8))) short;
using f32x4  = __attribute__((ext_vector_type(4))) float;

__device__ __forceinline__ float loadf(const void* p, size_t i, int isbf16) {
    return isbf16 ? __bfloat162float(((const __hip_bfloat16*)p)[i])
                  : ((const float*)p)[i];
}

__device__ __forceinline__ float leaky(float a) {
    return a > 0.f ? a : NEG_SLOPE * a;
}

__device__ __forceinline__ unsigned short f2bs(float f) {
    __hip_bfloat16 b = __float2bfloat16(f);
    return *reinterpret_cast<unsigned short*>(&b);
}

__device__ __forceinline__ float bs2f(unsigned short u) {
    return __uint_as_float((unsigned)u << 16);
}

// ---------------- fused prep: detect dtype of 9 tensors + cvt small vecs ---

__global__ void prep_kernel(const void* x, int nx,
                            const void* W1, const void* as1w, const void* ad1w,
                            const void* b1, const void* W2, const void* as2w,
                            const void* ad2w, const void* b2,
                            float* as1wf, float* ad1wf, float* b1f,
                            float* as2wf, float* ad2wf, float* b2f,
                            int* flags) {
    const void* srcs[9] = {x, W1, as1w, ad1w, b1, W2, as2w, ad2w, b2};
    int ns[9] = {nx, IN_DIM * HID, HEADS * C1, HEADS * C1, HID,
                 HID * OUT_DIM, OUT_DIM, OUT_DIM, OUT_DIM};
    float* dsts[9] = {nullptr, nullptr, as1wf, ad1wf, b1f, nullptr, as2wf, ad2wf, b2f};

    int b = blockIdx.x;
    const unsigned short* u = (const unsigned short*)srcs[b];
    int n = ns[b];
    int nslots = n < 4096 ? n : 4096;
    int cnt = 0;
    for (int i = threadIdx.x; i < nslots; i += 256) {
        unsigned short a = u[i] & 0x7FFF;
        int e = a >> 7;
        if (a == 0 || (e >= 90 && e <= 140)) cnt++;
    }
    __shared__ int red[4];
    __shared__ int flagS;
    for (int o = 32; o > 0; o >>= 1) cnt += __shfl_down(cnt, o);
    if ((threadIdx.x & 63) == 0) red[threadIdx.x >> 6] = cnt;
    __syncthreads();
    if (threadIdx.x == 0) {
        int tot = red[0] + red[1] + red[2] + red[3];
        int f = (tot * 10 >= nslots * 8) ? 1 : 0;
        flags[b] = f;
        flagS = f;
    }
    __syncthreads();
    int f = flagS;
    float* d = dsts[b];
    if (d) {
        for (int i = threadIdx.x; i < n; i += 256) d[i] = loadf(srcs[b], i, f);
    }
}

// transpose W1 [256][256] -> W1T [n][k] bf16, W2 [256][128] -> W2T [n][k]
__global__ void tpose_kernel(const void* W1, const void* W2,
                             const int* flags,
                             __hip_bfloat16* __restrict__ W1T,
                             __hip_bfloat16* __restrict__ W2T) {
    int b = blockIdx.x;
    int t = threadIdx.x;
    if (b < 256) {
        int i = b * 256 + t;
        int k = i >> 8, n = i & 255;
        W1T[n * 256 + k] = __float2bfloat16(loadf(W1, i, flags[1]));
    } else {
        int i = (b - 256) * 256 + t;
        int k = i >> 7, n = i & 127;
        W2T[n * 256 + k] = __float2bfloat16(loadf(W2, i, flags[5]));
    }
}

// ---------------- CSR build ----------------

__global__ void count_kernel(const int* __restrict__ ei, int E, int EP,
                             int* __restrict__ deg) {
    int idx = blockIdx.x * blockDim.x + threadIdx.x;
    if (idx >= EP) return;
    int d = (idx < E) ? ei[E + idx] : (idx - E);
    atomicAdd(&deg[d], 1);
}

__global__ __launch_bounds__(256) void psum_kernel(const int* __restrict__ deg,
                                                   int* __restrict__ bsum, int n) {
    int i = blockIdx.x * 256 + threadIdx.x;
    int v = (i < n) ? deg[i] : 0;
#pragma unroll
    for (int o = 32; o > 0; o >>= 1) v += __shfl_down(v, o);
    __shared__ int red[4];
    if ((threadIdx.x & 63) == 0) red[threadIdx.x >> 6] = v;
    __syncthreads();
    if (threadIdx.x == 0) bsum[blockIdx.x] = red[0] + red[1] + red[2] + red[3];
}

__global__ __launch_bounds__(1024) void bscan_kernel(int* __restrict__ bsum, int nb) {
    __shared__ int sh[1024];
    int t = threadIdx.x;
    int v = (t < nb) ? bsum[t] : 0;
    sh[t] = v;
    __syncthreads();
    for (int d = 1; d < 1024; d <<= 1) {
        int u = (t >= d) ? sh[t - d] : 0;
        __syncthreads();
        sh[t] += u;
        __syncthreads();
    }
    if (t < nb) bsum[t] = sh[t] - v;
}

__global__ __launch_bounds__(256) void wscan_kernel(int* __restrict__ deg,
                                                    const int* __restrict__ bsum,
                                                    int* __restrict__ offs, int n) {
    __shared__ int sh[256];
    int b = blockIdx.x;
    int i = b * 256 + threadIdx.x;
    int v = (i < n) ? deg[i] : 0;
    sh[threadIdx.x] = v;
    __syncthreads();
    for (int d = 1; d < 256; d <<= 1) {
        int u = (threadIdx.x >= d) ? sh[threadIdx.x - d] : 0;
        __syncthreads();
        sh[threadIdx.x] += u;
        __syncthreads();
    }
    int excl = sh[threadIdx.x] - v + bsum[b];
    if (i < n) {
        offs[i] = excl;
        deg[i]  = excl;
        if (i == n - 1) offs[n] = excl + v;
    }
}

__global__ void fill_kernel(const int* __restrict__ ei, int E, int EP,
                            int* __restrict__ cursor, int* __restrict__ ssrc) {
    int idx = blockIdx.x * blockDim.x + threadIdx.x;
    if (idx >= EP) return;
    int src = (idx < E) ? ei[idx]     : (idx - E);
    int dst = (idx < E) ? ei[E + idx] : (idx - E);
    int pos = atomicAdd(&cursor[dst], 1);
    ssrc[pos] = src;
}

// ---------------- MFMA GEMM: C[M,Nn] = A[M,K](bf16|f32) @ BT[Nn,K]^T -------

__device__ __forceinline__ void store_out(float* C, size_t i, float v) { C[i] = v; }
__device__ __forceinline__ void store_out(__hip_bfloat16* C, size_t i, float v) {
    C[i] = __float2bfloat16(v);
}

template <typename OutT>
__global__ __launch_bounds__(256) void gemm_mfma(
    const void* __restrict__ A0, const int* aflagp,
    const __hip_bfloat16* __restrict__ BT,
    OutT* __restrict__ C, int M, int Nn, int K) {
    constexpr int BM = 128, BN = 128, BK = 32;
    constexpr int LDK = BK + 8;
    __shared__ __hip_bfloat16 As[BM * LDK];
    __shared__ __hip_bfloat16 Bs[BN * LDK];

    const int aflag = aflagp ? *aflagp : 1;
    const int tid  = threadIdx.x;
    const int lane = tid & 63;
    const int wv   = tid >> 6;
    const int wm   = (wv >> 1) * 64;
    const int wn   = (wv & 1) * 64;
    const int l15  = lane & 15;
    const int quad = lane >> 4;

    const int bm = blockIdx.y * BM;
    const int bn = blockIdx.x * BN;

    f32x4 acc[4][4] = {};

    for (int k0 = 0; k0 < K; k0 += BK) {
#pragma unroll
        for (int i = 0; i < 2; ++i) {
            int c    = tid + i * 256;
            int row  = c >> 2;
            int koff = (c & 3) * 8;
            int grow = bm + row;
            short8 av = {};
            if (grow < M) {
                if (aflag) {
                    av = *(const short8*)((const __hip_bfloat16*)A0 +
                                          (size_t)grow * K + k0 + koff);
                } else {
                    const float* ap = (const float*)A0 + (size_t)grow * K + k0 + koff;
                    float4 f0 = *(const float4*)ap;
                    float4 f1 = *(const float4*)(ap + 4);
                    av[0] = (short)f2bs(f0.x); av[1] = (short)f2bs(f0.y);
                    av[2] = (short)f2bs(f0.z); av[3] = (short)f2bs(f0.w);
                    av[4] = (short)f2bs(f1.x); av[5] = (short)f2bs(f1.y);
                    av[6] = (short)f2bs(f1.z); av[7] = (short)f2bs(f1.w);
                }
            }
            *(short8*)&As[row * LDK + koff] = av;
            short8 bv = *(const short8*)(BT + (size_t)(bn + row) * K + k0 + koff);
            *(short8*)&Bs[row * LDK + koff] = bv;
        }
        __syncthreads();

        short8 af[4], bf[4];
#pragma unroll
        for (int f = 0; f < 4; ++f) {
            af[f] = *(const short8*)&As[(wm + f * 16 + l15) * LDK + quad * 8];
            bf[f] = *(const short8*)&Bs[(wn + f * 16 + l15) * LDK + quad * 8];
        }
#pragma unroll
        for (int fm = 0; fm < 4; ++fm)
#pragma unroll
            for (int fn = 0; fn < 4; ++fn)
                acc[fm][fn] = __builtin_amdgcn_mfma_f32_16x16x32_bf16(
                    af[fm], bf[fn], acc[fm][fn], 0, 0, 0);
        __syncthreads();
    }

#pragma unroll
    for (int fm = 0; fm < 4; ++fm) {
#pragma unroll
        for (int r = 0; r < 4; ++r) {
            int grow = bm + wm + fm * 16 + quad * 4 + r;
            if (grow >= M) continue;
#pragma unroll
            for (int fn = 0; fn < 4; ++fn) {
                int gcol = bn + wn + fn * 16 + l15;
                store_out(C, (size_t)grow * Nn + gcol, acc[fm][fn][r]);
            }
        }
    }
}

// ---------------- attention scalar products (per node) ----------------

__global__ void alpha1_kernel(const __hip_bfloat16* __restrict__ h1,
                              const float* __restrict__ asw,
                              const float* __restrict__ adw,
                              float* __restrict__ as1, float* __restrict__ ad1,
                              int n) {
    int gt = blockIdx.x * blockDim.x + threadIdx.x;
    int v = gt >> 6;
    int lane = gt & 63;
    if (v >= n) return;
#pragma unroll
    for (int h = 0; h < HEADS; ++h) {
        float val = __bfloat162float(h1[(size_t)v * HID + h * C1 + lane]);
        float s = val * asw[h * C1 + lane];
        float d = val * adw[h * C1 + lane];
#pragma unroll
        for (int o = 32; o > 0; o >>= 1) {
            s += __shfl_down(s, o);
            d += __shfl_down(d, o);
        }
        if (lane == 0) {
            as1[v * HEADS + h] = s;
            ad1[v * HEADS + h] = d;
        }
    }
}

__global__ void alpha2_kernel(const float* __restrict__ h2,
                              const float* __restrict__ asw,
                              const float* __restrict__ adw,
                              float* __restrict__ as2, float* __restrict__ ad2,
                              int n) {
    int gt = blockIdx.x * blockDim.x + threadIdx.x;
    int v = gt >> 6;
    int lane = gt & 63;
    if (v >= n) return;
    float v0 = h2[(size_t)v * OUT_DIM + lane];
    float v1 = h2[(size_t)v * OUT_DIM + 64 + lane];
    float s = v0 * asw[lane] + v1 * asw[64 + lane];
    float d = v0 * adw[lane] + v1 * adw[64 + lane];
#pragma unroll
    for (int o = 32; o > 0; o >>= 1) {
        s += __shfl_down(s, o);
        d += __shfl_down(d, o);
    }
    if (lane == 0) { as2[v] = s; ad2[v] = d; }
}

// ---------------- edge softmax ----------------
// L1 alpha layout: [head][edge]  (alpha[h*EP + i]) for slice-contiguous reads.

__global__ __launch_bounds__(256) void attn1_kernel(
    const float* __restrict__ as1, const float* __restrict__ ad1,
    const int* __restrict__ offs, const int* __restrict__ ssrc,
    float* __restrict__ alpha, int n, int EP) {
    int v = blockIdx.x * 4 + (threadIdx.x >> 6);
    if (v >= n) return;
    int l = threadIdx.x & 63;
    int h = l & 3;
    int eoff = l >> 2;
    int start = offs[v], end = offs[v + 1];
    float adv = ad1[v * 4 + h];
    float* alh = alpha + (size_t)h * EP;

    float m = -1e30f;
    for (int i = start + eoff; i < end; i += 16)
        m = fmaxf(m, leaky(as1[ssrc[i] * 4 + h] + adv));
#pragma unroll
    for (int o = 4; o < 64; o <<= 1) m = fmaxf(m, __shfl_xor(m, o));

    float den = 0.f;
    for (int i = start + eoff; i < end; i += 16) {
        float w = __expf(leaky(as1[ssrc[i] * 4 + h] + adv) - m);
        alh[i] = w;
        den += w;
    }
#pragma unroll
    for (int o = 4; o < 64; o <<= 1) den += __shfl_xor(den, o);
    float r = 1.f / (den + 1e-16f);

    for (int i = start + eoff; i < end; i += 16) alh[i] *= r;
}

__global__ __launch_bounds__(256) void attn2_kernel(
    const float* __restrict__ as2, const float* __restrict__ ad2,
    const int* __restrict__ offs, const int* __restrict__ ssrc,
    float* __restrict__ alpha, int n) {
    int v = blockIdx.x * 4 + (threadIdx.x >> 6);
    if (v >= n) return;
    int l = threadIdx.x & 63;
    int start = offs[v], end = offs[v + 1];
    float adv = ad2[v];

    float m = -1e30f;
    for (int i = start + l; i < end; i += 64)
        m = fmaxf(m, leaky(as2[ssrc[i]] + adv));
#pragma unroll
    for (int o = 1; o < 64; o <<= 1) m = fmaxf(m, __shfl_xor(m, o));

    float den = 0.f;
    for (int i = start + l; i < end; i += 64) {
        float w = __expf(leaky(as2[ssrc[i]] + adv) - m);
        alpha[i] = w;
        den += w;
    }
#pragma unroll
    for (int o = 1; o < 64; o <<= 1) den += __shfl_xor(den, o);
    float r = 1.f / (den + 1e-16f);

    for (int i = start + l; i < end; i += 64) alpha[i] *= r;
}

// ---------------- XCD-local weighted-gather aggregation --------------------
// Channel dim split into 8 slices; slice = blockIdx & 7 -> XCD (round-robin
// heuristic). Slice working set of h fits one XCD's 4 MiB L2.
// Block = 256 thr = 4 waves; wave = 8 nodes x 8 lanes; lane = 8B of channels.

// Layer 1: h1 = N x 64 ushort4; slice c covers ushort4 cols c*8..c*8+7
// (32 channels, head = c>>1). alpha layout [head][EP].
__global__ __launch_bounds__(256) void agg1x_kernel(
    const ushort4* __restrict__ h1, const float* __restrict__ alpha,
    const int* __restrict__ offs, const int* __restrict__ ssrc,
    const float* __restrict__ bias1, ushort4* __restrict__ g, int n, int EP) {
    int c  = blockIdx.x & 7;
    int vb = blockIdx.x >> 3;
    int lane = threadIdx.x & 63;
    int v = vb * 32 + (threadIdx.x >> 6) * 8 + (lane >> 3);
    if (v >= n) return;
    int col = c * 8 + (lane & 7);          // ushort4 column 0..63
    const float* al = alpha + (size_t)(c >> 1) * EP;
    int start = offs[v], end = offs[v + 1];

    float a0 = 0.f, a1 = 0.f, a2 = 0.f, a3 = 0.f;
    int i = start;
    for (; i + 4 <= end; i += 4) {
        int s0 = ssrc[i], s1 = ssrc[i + 1], s2 = ssrc[i + 2], s3 = ssrc[i + 3];
        float w0 = al[i], w1 = al[i + 1], w2 = al[i + 2], w3 = al[i + 3];
        ushort4 p0 = h1[(size_t)s0 * 64 + col];
        ushort4 p1 = h1[(size_t)s1 * 64 + col];
        ushort4 p2 = h1[(size_t)s2 * 64 + col];
        ushort4 p3 = h1[(size_t)s3 * 64 + col];
        a0 += w0 * bs2f(p0.x) + w1 * bs2f(p1.x) + w2 * bs2f(p2.x) + w3 * bs2f(p3.x);
        a1 += w0 * bs2f(p0.y) + w1 * bs2f(p1.y) + w2 * bs2f(p2.y) + w3 * bs2f(p3.y);
        a2 += w0 * bs2f(p0.z) + w1 * bs2f(p1.z) + w2 * bs2f(p2.z) + w3 * bs2f(p3.z);
        a3 += w0 * bs2f(p0.w) + w1 * bs2f(p1.w) + w2 * bs2f(p2.w) + w3 * bs2f(p3.w);
    }
    for (; i < end; ++i) {
        int s = ssrc[i];
        float w = al[i];
        ushort4 p = h1[(size_t)s * 64 + col];
        a0 += w * bs2f(p.x);
        a1 += w * bs2f(p.y);
        a2 += w * bs2f(p.z);
        a3 += w * bs2f(p.w);
    }
    float4 bq = *(const float4*)&bias1[4 * col];
    float o0 = a0 + bq.x, o1 = a1 + bq.y, o2 = a2 + bq.z, o3 = a3 + bq.w;
    o0 = 0.5f * o0 * (1.0f + erff(o0 * 0.70710678f));
    o1 = 0.5f * o1 * (1.0f + erff(o1 * 0.70710678f));
    o2 = 0.5f * o2 * (1.0f + erff(o2 * 0.70710678f));
    o3 = 0.5f * o3 * (1.0f + erff(o3 * 0.70710678f));
    ushort4 r;
    r.x = f2bs(o0); r.y = f2bs(o1); r.z = f2bs(o2); r.w = f2bs(o3);
    g[(size_t)v * 64 + col] = r;
}

// Layer 2: h2 = N x 64 float2; slice c covers float2 cols c*8..c*8+7.
__global__ __launch_bounds__(256) void agg2x_kernel(
    const float2* __restrict__ h2, const float* __restrict__ alpha,
    const int* __restrict__ offs, const int* __restrict__ ssrc,
    const float* __restrict__ bias2, void* __restrict__ out,
    const int* outflagp, int n) {
    int c  = blockIdx.x & 7;
    int vb = blockIdx.x >> 3;
    int lane = threadIdx.x & 63;
    int v = vb * 32 + (threadIdx.x >> 6) * 8 + (lane >> 3);
    if (v >= n) return;
    int col = c * 8 + (lane & 7);          // float2 column 0..63
    int start = offs[v], end = offs[v + 1];

    float nx = 0.f, ny = 0.f;
    int i = start;
    for (; i + 4 <= end; i += 4) {
        int s0 = ssrc[i], s1 = ssrc[i + 1], s2 = ssrc[i + 2], s3 = ssrc[i + 3];
        float w0 = alpha[i], w1 = alpha[i + 1], w2 = alpha[i + 2], w3 = alpha[i + 3];
        float2 p0 = h2[(size_t)s0 * 64 + col];
        float2 p1 = h2[(size_t)s1 * 64 + col];
        float2 p2 = h2[(size_t)s2 * 64 + col];
        float2 p3 = h2[(size_t)s3 * 64 + col];
        nx += w0 * p0.x + w1 * p1.x + w2 * p2.x + w3 * p3.x;
        ny += w0 * p0.y + w1 * p1.y + w2 * p2.y + w3 * p3.y;
    }
    for (; i < end; ++i) {
        int s = ssrc[i];
        float w = alpha[i];
        float2 p = h2[(size_t)s * 64 + col];
        nx += w * p.x;
        ny += w * p.y;
    }
    float ox = nx + bias2[2 * col];
    float oy = ny + bias2[2 * col + 1];
    size_t oi = (size_t)v * 64 + col;
    if (*outflagp) {
        __hip_bfloat162 r;
        r.x = __float2bfloat16(ox);
        r.y = __float2bfloat16(oy);
        ((__hip_bfloat162*)out)[oi] = r;
    } else {
        ((float2*)out)[oi] = make_float2(ox, oy);
    }
}

// ---------------------------------------------------------------------------

static inline char* alignp(char* p, size_t a) {
    return (char*)(((uintptr_t)p + a - 1) & ~(uintptr_t)(a - 1));
}

extern "C" void kernel_launch(void* const* d_in, const int* in_sizes, int n_in,
                              void* d_out, int out_size, void* d_ws, size_t ws_size,
                              hipStream_t stream) {
    const void* x    = d_in[0];
    const int*  ei   = (const int*)d_in[1];
    const void* W1   = d_in[2];
    const void* as1w = d_in[3];
    const void* ad1w = d_in[4];
    const void* b1   = d_in[5];
    const void* W2   = d_in[6];
    const void* as2w = d_in[7];
    const void* ad2w = d_in[8];
    const void* b2   = d_in[9];

    const int N  = out_size / OUT_DIM;       // 50000
    const int E  = in_sizes[1] / 2;          // 800000
    const int EP = E + N;
    const int NB = (N + 255) / 256;

    // ---- workspace carve (~74.2 MB; h1/h2 union) ----
    char* p = (char*)d_ws;
    __hip_bfloat16* h1 = (__hip_bfloat16*)p;
    float*          h2 = (float*)p;           p += (size_t)N * HID * 2;
    __hip_bfloat16* g  = (__hip_bfloat16*)p;  p += (size_t)N * HID * 2;
    float* as1wf = (float*)p;                 p += 256 * 4;
    float* ad1wf = (float*)p;                 p += 256 * 4;
    float* b1f   = (float*)p;                 p += 256 * 4;
    float* as2wf = (float*)p;                 p += 128 * 4;
    float* ad2wf = (float*)p;                 p += 128 * 4;
    float* b2f   = (float*)p;                 p += 128 * 4;
    float* as1   = (float*)p;                 p += (size_t)N * HEADS * 4;
    float* ad1   = (float*)p;                 p += (size_t)N * HEADS * 4;
    float* as2   = (float*)p;                 p += (size_t)N * 4;
    float* ad2   = (float*)p;                 p += (size_t)N * 4;
    float* al1   = (float*)p;                 p += (size_t)EP * HEADS * 4;  // [head][EP]
    float* al2   = (float*)p;                 p += (size_t)EP * 4;
    int*   flags = (int*)p;                   p += 16 * 4;
    int*   deg   = (int*)p;                   p += (size_t)N * 4;
    int*   offs  = (int*)p;                   p += (size_t)(N + 1) * 4;
    int*   bsum  = (int*)p;                   p += (size_t)1024 * 4;
    int*   ssrc  = (int*)p;                   p += (size_t)EP * 4;
    p = alignp(p, 64);
    __hip_bfloat16* W1T = (__hip_bfloat16*)p; p += (size_t)HID * IN_DIM * 2;
    __hip_bfloat16* W2T = (__hip_bfloat16*)p; p += (size_t)OUT_DIM * HID * 2;

    // ---- prep ----
    prep_kernel<<<9, 256, 0, stream>>>(x, in_sizes[0], W1, as1w, ad1w, b1,
                                       W2, as2w, ad2w, b2,
                                       as1wf, ad1wf, b1f, as2wf, ad2wf, b2f,
                                       flags);
    tpose_kernel<<<384, 256, 0, stream>>>(W1, W2, flags, W1T, W2T);

    // ---- CSR build ----
    hipMemsetAsync(deg, 0, (size_t)N * sizeof(int), stream);
    {
        int blk = 256, grd = (EP + blk - 1) / blk;
        count_kernel<<<grd, blk, 0, stream>>>(ei, E, EP, deg);
        psum_kernel<<<NB, 256, 0, stream>>>(deg, bsum, N);
        bscan_kernel<<<1, 1024, 0, stream>>>(bsum, NB);
        wscan_kernel<<<NB, 256, 0, stream>>>(deg, bsum, offs, N);
        fill_kernel<<<grd, blk, 0, stream>>>(ei, E, EP, deg, ssrc);
    }

    const int aggGrid = ((N + 31) / 32) * 8;

    // ---- layer 1 ----
    gemm_mfma<__hip_bfloat16><<<dim3(HID / 128, (N + 127) / 128), 256, 0, stream>>>(
        x, flags + 0, W1T, h1, N, HID, IN_DIM);
    alpha1_kernel<<<((N * 64) + 255) / 256, 256, 0, stream>>>(h1, as1wf, ad1wf, as1, ad1, N);
    attn1_kernel<<<(N + 3) / 4, 256, 0, stream>>>(as1, ad1, offs, ssrc, al1, N, EP);
    agg1x_kernel<<<aggGrid, 256, 0, stream>>>((const ushort4*)h1, al1, offs, ssrc,
                                              b1f, (ushort4*)g, N, EP);

    // ---- layer 2 (h2 reuses h1's buffer) ----
    gemm_mfma<float><<<dim3(OUT_DIM / 128, (N + 127) / 128), 256, 0, stream>>>(
        g, nullptr, W2T, h2, N, OUT_DIM, HID);
    alpha2_kernel<<<((N * 64) + 255) / 256, 256, 0, stream>>>(h2, as2wf, ad2wf, as2, ad2, N);
    attn2_kernel<<<(N + 3) / 4, 256, 0, stream>>>(as2, ad2, offs, ssrc, al2, N);
    agg2x_kernel<<<aggGrid, 256, 0, stream>>>((const float2*)h2, al2, offs, ssrc,
                                              b2f, d_out, flags + 0, N);
}